// Round 6
// baseline (96.869 us; speedup 1.0000x reference)
//
#include <hip/hip_runtime.h>

constexpr int NUM_HEADS      = 32;
constexpr int HEAD_DIM       = 128;
constexpr int NUM_KV         = 8;
constexpr int GROUP          = 4;                     // query heads per kv head
constexpr int BLOCK_SIZE     = 16;
constexpr int BLOCKS_PER_SEQ = 64;
constexpr int BATCH          = 64;
constexpr int SEQ            = BLOCKS_PER_SEQ * BLOCK_SIZE;   // 1024
constexpr int KV_ROW         = NUM_KV * HEAD_DIM;             // 1024 floats / slot-row
constexpr int SPLIT          = 16;                   // flash-decode partitions
constexpr int TOK            = SEQ / SPLIT;          // 64 tokens per partition
constexpr float SCALE        = 0.08838834764831845f;

// workspace layout (floats): unnormalized partial O, then m, then l
constexpr size_t WS_O = 0;
constexpr size_t WS_M = (size_t)BATCH * NUM_KV * SPLIT * GROUP * HEAD_DIM; // 4,194,304
constexpr size_t WS_L = WS_M + (size_t)BATCH * NUM_KV * SPLIT * GROUP;     // +32,768
// total ~17 MB of d_ws

// One wg (256 thr = 4 waves) per (b, split). The wg consumes WHOLE 64 KB
// cache blocks (all 8 kv heads) so DRAM sees contiguous 64 KB streams
// instead of random 512 B granules (R1-R5 plateaued at ~3.3 TB/s =
// activate-rate limit of 512 B/row-activate random access).
// Row (tok,kvh) is contiguous: 4 waves tile 4 KB per token; wave w owns
// kvh {2w, 2w+1}; half-wave = one kvh; lane = 4 dims. Softmax is
// wave-local, outputs per-half-wave disjoint -> NO __syncthreads at all.
__global__ __launch_bounds__(256, 4) void paged_attn_split(
    const float* __restrict__ q,            // [B, 32, 128]
    const float* __restrict__ knew,         // [B, 8, 128]
    const float* __restrict__ vnew,         // [B, 8, 128]
    const float* __restrict__ kcache,       // [4096, 16, 8, 128]
    const float* __restrict__ vcache,       // [4096, 16, 8, 128]
    const int*   __restrict__ slot_mapping, // [B]
    const int*   __restrict__ block_tables, // [B, 64]
    float*       __restrict__ ws)
{
    const int wg   = (int)blockIdx.x;       // b*SPLIT + sp
    const int sp   = wg & (SPLIT - 1);
    const int b    = wg >> 4;
    const int tid  = (int)threadIdx.x;
    const int lane = tid & 63;
    const int w    = tid >> 6;
    const int half = lane >> 5;
    const int dl   = lane & 31;             // dim-lane: floats [dl*4, dl*4+4)
    const int kvh  = 2 * w + half;          // this half-wave's kv head

    __shared__ float4 s_p[TOK][NUM_KV];     // probs [t][kvh] as float4 over g (8 KB)

    // --- token -> source slot, one per lane (TOK == 64 == wave size).
    // Reference scatters fresh k/v into the cache before gathering; we
    // redirect reads instead of mutating inputs. Wave-redundant, register-only.
    int rsrc;
    {
        int blk  = block_tables[b * BLOCKS_PER_SEQ + sp * (TOK / BLOCK_SIZE) + (lane >> 4)];
        int slot = blk * BLOCK_SIZE + (lane & 15);
        int r = slot;
        #pragma unroll
        for (int i = 0; i < BATCH; i += 4) {
            int4 sm = *reinterpret_cast<const int4*>(&slot_mapping[i]);
            if (sm.x == slot) r = -1 - i;
            if (sm.y == slot) r = -2 - i;
            if (sm.z == slot) r = -3 - i;
            if (sm.w == slot) r = -4 - i;
        }
        rsrc = r;
    }

    // q fragment for this half-wave's kvh: 4 heads x 4 dims (SCALE folded in)
    float4 qh[GROUP];
    #pragma unroll
    for (int g = 0; g < GROUP; ++g) {
        float4 t = *reinterpret_cast<const float4*>(
            &q[((size_t)b * NUM_HEADS + kvh * GROUP + g) * HEAD_DIM + dl * 4]);
        qh[g] = make_float4(t.x * SCALE, t.y * SCALE, t.z * SCALE, t.w * SCALE);
    }
    const int laneoff = kvh * HEAD_DIM + dl * 4;

    // ---- Phase 1: scores. Wave instruction = 1 KB contiguous (2 adjacent
    // kvh rows); 4 waves tile 4 KB/token; 8-round batches keep 8 KB/wave
    // in flight while streaming each 64 KB block densely.
    #pragma unroll
    for (int rb = 0; rb < TOK / 8; ++rb) {
        float4 kv[8];
        #pragma unroll
        for (int j = 0; j < 8; ++j) {
            int src = __shfl(rsrc, rb * 8 + j);
            const float* kp = (src >= 0)
                ? kcache + (size_t)src * KV_ROW
                : knew   + (size_t)(-1 - src) * KV_ROW;
            kv[j] = *reinterpret_cast<const float4*>(kp + laneoff);
        }
        #pragma unroll
        for (int j = 0; j < 8; ++j) {
            float p0 = qh[0].x*kv[j].x + qh[0].y*kv[j].y + qh[0].z*kv[j].z + qh[0].w*kv[j].w;
            float p1 = qh[1].x*kv[j].x + qh[1].y*kv[j].y + qh[1].z*kv[j].z + qh[1].w*kv[j].w;
            float p2 = qh[2].x*kv[j].x + qh[2].y*kv[j].y + qh[2].z*kv[j].z + qh[2].w*kv[j].w;
            float p3 = qh[3].x*kv[j].x + qh[3].y*kv[j].y + qh[3].z*kv[j].z + qh[3].w*kv[j].w;
            #pragma unroll
            for (int off = 1; off < 32; off <<= 1) {   // reduce within half-wave
                p0 += __shfl_xor(p0, off);
                p1 += __shfl_xor(p1, off);
                p2 += __shfl_xor(p2, off);
                p3 += __shfl_xor(p3, off);
            }
            if (dl == 0) s_p[rb * 8 + j][kvh] = make_float4(p0, p1, p2, p3);
        }
    }

    // ---- Phase 2: wave-local softmax stats over TOK=64, per (kvh, g) ----
    float4 mv, lv;
    {
        float4 a = s_p[dl][kvh], c = s_p[dl + 32][kvh];
        mv = make_float4(fmaxf(a.x, c.x), fmaxf(a.y, c.y),
                         fmaxf(a.z, c.z), fmaxf(a.w, c.w));
        #pragma unroll
        for (int off = 1; off < 32; off <<= 1) {
            mv.x = fmaxf(mv.x, __shfl_xor(mv.x, off));
            mv.y = fmaxf(mv.y, __shfl_xor(mv.y, off));
            mv.z = fmaxf(mv.z, __shfl_xor(mv.z, off));
            mv.w = fmaxf(mv.w, __shfl_xor(mv.w, off));
        }
        float4 ea = make_float4(__expf(a.x - mv.x), __expf(a.y - mv.y),
                                __expf(a.z - mv.z), __expf(a.w - mv.w));
        float4 ec = make_float4(__expf(c.x - mv.x), __expf(c.y - mv.y),
                                __expf(c.z - mv.z), __expf(c.w - mv.w));
        s_p[dl][kvh] = ea;
        s_p[dl + 32][kvh] = ec;
        lv = make_float4(ea.x + ec.x, ea.y + ec.y, ea.z + ec.z, ea.w + ec.w);
        #pragma unroll
        for (int off = 1; off < 32; off <<= 1) {
            lv.x += __shfl_xor(lv.x, off);
            lv.y += __shfl_xor(lv.y, off);
            lv.z += __shfl_xor(lv.z, off);
            lv.w += __shfl_xor(lv.w, off);
        }
        if (dl == 0) {
            size_t mi = ((size_t)(b * NUM_KV + kvh) * SPLIT + sp) * GROUP;
            *reinterpret_cast<float4*>(&ws[WS_M + mi]) = mv;
            *reinterpret_cast<float4*>(&ws[WS_L + mi]) = lv;
        }
    }

    // ---- Phase 3: unnormalized partial O, same streaming pattern ----
    {
        float4 a0 = {0,0,0,0}, a1 = a0, a2 = a0, a3 = a0;
        #pragma unroll
        for (int rb = 0; rb < TOK / 8; ++rb) {
            float4 vv[8];
            #pragma unroll
            for (int j = 0; j < 8; ++j) {
                int src = __shfl(rsrc, rb * 8 + j);
                const float* vp = (src >= 0)
                    ? vcache + (size_t)src * KV_ROW
                    : vnew   + (size_t)(-1 - src) * KV_ROW;
                vv[j] = *reinterpret_cast<const float4*>(vp + laneoff);
            }
            #pragma unroll
            for (int j = 0; j < 8; ++j) {
                float4 pv = s_p[rb * 8 + j][kvh];   // LDS broadcast per half
                a0.x += pv.x*vv[j].x; a0.y += pv.x*vv[j].y; a0.z += pv.x*vv[j].z; a0.w += pv.x*vv[j].w;
                a1.x += pv.y*vv[j].x; a1.y += pv.y*vv[j].y; a1.z += pv.y*vv[j].z; a1.w += pv.y*vv[j].w;
                a2.x += pv.z*vv[j].x; a2.y += pv.z*vv[j].y; a2.z += pv.z*vv[j].z; a2.w += pv.z*vv[j].w;
                a3.x += pv.w*vv[j].x; a3.y += pv.w*vv[j].y; a3.z += pv.w*vv[j].z; a3.w += pv.w*vv[j].w;
            }
        }
        // half-wave owns (kvh, g, dims dl*4..+4) exclusively: direct store
        size_t ob = WS_O + (((size_t)(b * NUM_KV + kvh) * SPLIT + sp) * GROUP) * HEAD_DIM + dl * 4;
        *reinterpret_cast<float4*>(&ws[ob + 0 * HEAD_DIM]) = a0;
        *reinterpret_cast<float4*>(&ws[ob + 1 * HEAD_DIM]) = a1;
        *reinterpret_cast<float4*>(&ws[ob + 2 * HEAD_DIM]) = a2;
        *reinterpret_cast<float4*>(&ws[ob + 3 * HEAD_DIM]) = a3;
    }
}

// Log-sum-exp combine of SPLIT partials per (b, kvh, g). 2048 blocks x 128 thr.
__global__ __launch_bounds__(128) void paged_attn_combine(
    const float* __restrict__ ws, float* __restrict__ out)
{
    const int hb  = (int)blockIdx.x;        // (b*KV+kvh)*GROUP + g
    const int g   = hb & 3;
    const int bk  = hb >> 2;
    const int kvh = bk & 7;
    const int b   = bk >> 3;
    const int d   = (int)threadIdx.x;

    float m[SPLIT];
    float mstar = -1e30f;
    #pragma unroll
    for (int s = 0; s < SPLIT; ++s) {
        m[s] = ws[WS_M + ((size_t)(bk * SPLIT + s) * GROUP) + g];
        mstar = fmaxf(mstar, m[s]);
    }
    float L = 0.f, acc = 0.f;
    #pragma unroll
    for (int s = 0; s < SPLIT; ++s) {
        float wgt = __expf(m[s] - mstar);
        L   += wgt * ws[WS_L + ((size_t)(bk * SPLIT + s) * GROUP) + g];
        acc += wgt * ws[WS_O + ((size_t)(bk * SPLIT + s) * GROUP + g) * HEAD_DIM + d];
    }
    out[((size_t)b * NUM_HEADS + kvh * GROUP + g) * HEAD_DIM + d] = acc / L;
}

extern "C" void kernel_launch(void* const* d_in, const int* in_sizes, int n_in,
                              void* d_out, int out_size, void* d_ws, size_t ws_size,
                              hipStream_t stream) {
    const float* q    = (const float*)d_in[0];
    const float* knew = (const float*)d_in[1];
    const float* vnew = (const float*)d_in[2];
    const float* kc   = (const float*)d_in[3];
    const float* vc   = (const float*)d_in[4];
    const int*   slot = (const int*)d_in[5];
    const int*   bt   = (const int*)d_in[6];
    float* out = (float*)d_out;
    float* ws  = (float*)d_ws;   // needs ~17 MB

    hipLaunchKernelGGL(paged_attn_split, dim3(BATCH * SPLIT), dim3(256),
                       0, stream, q, knew, vnew, kc, vc, slot, bt, ws);
    hipLaunchKernelGGL(paged_attn_combine, dim3(BATCH * NUM_KV * GROUP), dim3(128),
                       0, stream, ws, out);
}

// Round 7
// 86.195 us; speedup vs baseline: 1.1238x; 1.1238x over previous
//
#include <hip/hip_runtime.h>

constexpr int NUM_HEADS      = 32;
constexpr int HEAD_DIM       = 128;
constexpr int NUM_KV         = 8;
constexpr int GROUP          = 4;                     // query heads per kv head
constexpr int BLOCK_SIZE     = 16;
constexpr int BLOCKS_PER_SEQ = 64;
constexpr int BATCH          = 64;
constexpr int SEQ            = BLOCKS_PER_SEQ * BLOCK_SIZE;   // 1024
constexpr int KV_ROW         = NUM_KV * HEAD_DIM;             // 1024 floats / slot-row
constexpr int SPLIT          = 8;                    // flash-decode partitions
constexpr int TOK            = SEQ / SPLIT;          // 128 tokens per partition
constexpr int BLKS           = TOK / BLOCK_SIZE;     // 8 table entries per partition
constexpr float SCALE        = 0.08838834764831845f;

// workspace layout (floats): unnormalized partial O, then m, then l
constexpr size_t WS_O = 0;
constexpr size_t WS_M = (size_t)BATCH * NUM_KV * SPLIT * GROUP * HEAD_DIM; // 2,097,152
constexpr size_t WS_L = WS_M + (size_t)BATCH * NUM_KV * SPLIT * GROUP;     // +16,384

// One wg (256 thr = 4 waves) per (b, kv_head, split): partial flash-attention.
// This is the measured-best structure (R3, 85.9us): delivered load BW ~6.7
// TB/s (512 MB logical / ~78us split), above the 6.29 TB/s streaming-copy
// ceiling thanks to L3 hits on cross-batch block re-reads. R4 (barrier
// removal), R5 (deeper MLP), R6 (64KB granules) were all neutral/negative.
__global__ __launch_bounds__(256) void paged_attn_split(
    const float* __restrict__ q,            // [B, 32, 128]
    const float* __restrict__ knew,         // [B, 8, 128]
    const float* __restrict__ vnew,         // [B, 8, 128]
    const float* __restrict__ kcache,       // [4096, 16, 8, 128]
    const float* __restrict__ vcache,       // [4096, 16, 8, 128]
    const int*   __restrict__ slot_mapping, // [B]
    const int*   __restrict__ block_tables, // [B, 64]
    float*       __restrict__ ws)
{
    const int wg  = (int)blockIdx.x;        // ((b*KV + kvh)*SPLIT + sp)
    const int sp  = wg & (SPLIT - 1);
    const int bk  = wg >> 3;                // b*KV + kvh
    const int kvh = bk & 7;
    const int b   = bk >> 3;
    const int tid = (int)threadIdx.x;
    const int lane = tid & 63;
    const int wave = tid >> 6;

    __shared__ int   s_row[TOK];              // >=0: cache slot-row; <0: override -1-i
    __shared__ float s_p[TOK][GROUP];         // scores -> exp(score - m), [t][g]
    __shared__ float s_o[4][GROUP][HEAD_DIM]; // per-wave partial O (8 KB)
    __shared__ int   s_bt[BLKS];
    __shared__ int   s_slot[BATCH];

    if (tid < BLKS) s_bt[tid] = block_tables[b * BLOCKS_PER_SEQ + sp * BLKS + tid];
    if (tid >= 64 && tid < 64 + BATCH) s_slot[tid - 64] = slot_mapping[tid - 64];
    __syncthreads();

    // Token -> source row. Reference scatters fresh k/v into the cache before
    // the gather; we must not mutate inputs, so redirect reads instead.
    if (tid < TOK) {
        int slot = s_bt[tid >> 4] * BLOCK_SIZE + (tid & 15);
        int r = slot;
        #pragma unroll
        for (int i = 0; i < BATCH; ++i)
            if (s_slot[i] == slot) r = -1 - i;
        s_row[tid] = r;
    }

    const int h0 = kvh * GROUP;
    const size_t hoff = (size_t)kvh * HEAD_DIM;
    const int sub = lane >> 4;              // token sub-slot within wave (0..3)
    const int sl  = lane & 15;              // 16 lanes cooperate per token

    float4 qa[GROUP], qb[GROUP];            // q[g][sl*8 .. sl*8+8)
    #pragma unroll
    for (int g = 0; g < GROUP; ++g) {
        const float* qp = q + ((size_t)b * NUM_HEADS + h0 + g) * HEAD_DIM + sl * 8;
        qa[g] = *reinterpret_cast<const float4*>(qp);
        qb[g] = *reinterpret_cast<const float4*>(qp + 4);
    }
    __syncthreads();

    // ---- Phase 1: scores. 4 tokens/wave/iter, 16 lanes per token, f4 loads.
    #pragma unroll
    for (int t = wave * 4 + sub; t < TOK; t += 16) {
        int r = s_row[t];
        const float* krow = (r >= 0)
            ? kcache + (size_t)r * KV_ROW + hoff
            : knew   + (size_t)(-1 - r) * KV_ROW + hoff;
        float4 ka = *reinterpret_cast<const float4*>(krow + sl * 8);
        float4 kb = *reinterpret_cast<const float4*>(krow + sl * 8 + 4);
        float p[GROUP];
        #pragma unroll
        for (int g = 0; g < GROUP; ++g) {
            p[g] = qa[g].x * ka.x + qa[g].y * ka.y + qa[g].z * ka.z + qa[g].w * ka.w
                 + qb[g].x * kb.x + qb[g].y * kb.y + qb[g].z * kb.z + qb[g].w * kb.w;
        }
        #pragma unroll
        for (int off = 1; off < 16; off <<= 1) {
            #pragma unroll
            for (int g = 0; g < GROUP; ++g) p[g] += __shfl_xor(p[g], off);
        }
        if (sl == 0) {
            #pragma unroll
            for (int g = 0; g < GROUP; ++g) s_p[t][g] = p[g] * SCALE;
        }
    }
    __syncthreads();

    // ---- Phase 2: partial softmax stats over TOK=128 (wave = head) ----
    {
        const int g = wave;
        float v0 = s_p[lane][g], v1 = s_p[lane + 64][g];
        float m = fmaxf(v0, v1);
        #pragma unroll
        for (int off = 32; off; off >>= 1) m = fmaxf(m, __shfl_xor(m, off));
        float e0 = __expf(v0 - m), e1 = __expf(v1 - m);
        s_p[lane][g] = e0;
        s_p[lane + 64][g] = e1;
        float sum = e0 + e1;
        #pragma unroll
        for (int off = 32; off; off >>= 1) sum += __shfl_xor(sum, off);
        if (lane == 0) {
            ws[WS_M + (size_t)wg * GROUP + g] = m;
            ws[WS_L + (size_t)wg * GROUP + g] = sum;
        }
    }
    __syncthreads();

    // ---- Phase 3: unnormalized partial O. Tokens partitioned across waves
    // (no duplicate loads); half-wave per V row, float4/lane; acc = 4 dims x
    // 4 heads in registers; cross-half shfl + cross-wave LDS reduce at end.
    {
        const int half = lane >> 5;         // which of 2 tokens this iter
        const int dl   = lane & 31;         // dim-lane: dims [dl*4, dl*4+4)
        float4 a0 = {0,0,0,0}, a1 = a0, a2 = a0, a3 = a0;
        #pragma unroll 8
        for (int i = 0; i < TOK / 8; ++i) { // 16 iters, 2 tokens/iter/wave
            int t = wave * (TOK / 4) + i * 2 + half;
            int r = s_row[t];
            const float* vrow = (r >= 0)
                ? vcache + (size_t)r * KV_ROW + hoff
                : vnew   + (size_t)(-1 - r) * KV_ROW + hoff;
            float4 vv = *reinterpret_cast<const float4*>(vrow + dl * 4);
            float4 pv = *reinterpret_cast<const float4*>(&s_p[t][0]); // broadcast
            a0.x += pv.x * vv.x; a0.y += pv.x * vv.y; a0.z += pv.x * vv.z; a0.w += pv.x * vv.w;
            a1.x += pv.y * vv.x; a1.y += pv.y * vv.y; a1.z += pv.y * vv.z; a1.w += pv.y * vv.w;
            a2.x += pv.z * vv.x; a2.y += pv.z * vv.y; a2.z += pv.z * vv.z; a2.w += pv.z * vv.w;
            a3.x += pv.w * vv.x; a3.y += pv.w * vv.y; a3.z += pv.w * vv.z; a3.w += pv.w * vv.w;
        }
        // combine the two token-halves: lane d gets lane d+32's partial
        #define RED4(A) A.x += __shfl_xor(A.x, 32); A.y += __shfl_xor(A.y, 32); \
                        A.z += __shfl_xor(A.z, 32); A.w += __shfl_xor(A.w, 32);
        RED4(a0) RED4(a1) RED4(a2) RED4(a3)
        #undef RED4
        if (half == 0) {
            *reinterpret_cast<float4*>(&s_o[wave][0][dl * 4]) = a0;
            *reinterpret_cast<float4*>(&s_o[wave][1][dl * 4]) = a1;
            *reinterpret_cast<float4*>(&s_o[wave][2][dl * 4]) = a2;
            *reinterpret_cast<float4*>(&s_o[wave][3][dl * 4]) = a3;
        }
    }
    __syncthreads();

    // cross-wave reduce + store partial O: thread owns (g=wave, 2 dims)
    {
        const int g = wave;
        const int d = lane * 2;
        float ox = 0.f, oy = 0.f;
        #pragma unroll
        for (int w = 0; w < 4; ++w) {
            ox += s_o[w][g][d];
            oy += s_o[w][g][d + 1];
        }
        *reinterpret_cast<float2*>(
            ws + WS_O + ((size_t)wg * GROUP + g) * HEAD_DIM + d) = make_float2(ox, oy);
    }
}

// Log-sum-exp combine of SPLIT partials per (b, kvh, g). 2048 blocks x 128 thr.
__global__ __launch_bounds__(128) void paged_attn_combine(
    const float* __restrict__ ws, float* __restrict__ out)
{
    const int hb  = (int)blockIdx.x;        // (b*KV+kvh)*GROUP + g
    const int g   = hb & 3;
    const int bk  = hb >> 2;
    const int kvh = bk & 7;
    const int b   = bk >> 3;
    const int d   = (int)threadIdx.x;

    float m[SPLIT];
    float mstar = -1e30f;
    #pragma unroll
    for (int s = 0; s < SPLIT; ++s) {
        m[s] = ws[WS_M + ((size_t)(bk * SPLIT + s) * GROUP) + g];
        mstar = fmaxf(mstar, m[s]);
    }
    float L = 0.f, acc = 0.f;
    #pragma unroll
    for (int s = 0; s < SPLIT; ++s) {
        float w = __expf(m[s] - mstar);
        L   += w * ws[WS_L + ((size_t)(bk * SPLIT + s) * GROUP) + g];
        acc += w * ws[WS_O + ((size_t)(bk * SPLIT + s) * GROUP + g) * HEAD_DIM + d];
    }
    out[((size_t)b * NUM_HEADS + kvh * GROUP + g) * HEAD_DIM + d] = acc / L;
}

extern "C" void kernel_launch(void* const* d_in, const int* in_sizes, int n_in,
                              void* d_out, int out_size, void* d_ws, size_t ws_size,
                              hipStream_t stream) {
    const float* q    = (const float*)d_in[0];
    const float* knew = (const float*)d_in[1];
    const float* vnew = (const float*)d_in[2];
    const float* kc   = (const float*)d_in[3];
    const float* vc   = (const float*)d_in[4];
    const int*   slot = (const int*)d_in[5];
    const int*   bt   = (const int*)d_in[6];
    float* out = (float*)d_out;
    float* ws  = (float*)d_ws;   // needs 8.5 MB

    hipLaunchKernelGGL(paged_attn_split, dim3(BATCH * NUM_KV * SPLIT), dim3(256),
                       0, stream, q, knew, vnew, kc, vc, slot, bt, ws);
    hipLaunchKernelGGL(paged_attn_combine, dim3(BATCH * NUM_KV * GROUP), dim3(128),
                       0, stream, ws, out);
}